// Round 1
// baseline (4759.790 us; speedup 1.0000x reference)
//
#include <hip/hip_runtime.h>

#define HID_ 1000
#define NB 256
#define TT 49
#define DIN 192
#define NPAD 1024
#define KPAD 1024

typedef _Float16 f16;
typedef _Float16 f16x8 __attribute__((ext_vector_type(8)));
typedef float f32x4 __attribute__((ext_vector_type(4)));

__device__ __forceinline__ float sigmf_(float x) {
    return 1.0f / (1.0f + __expf(-x));
}
__device__ __forceinline__ float tanhf_(float x) {
    float ax = fabsf(x);
    float e = __expf(-2.0f * ax);
    float t = (1.0f - e) / (1.0f + e);
    return copysignf(t, x);
}

// Convert fp32 weight [4000][K] -> f16 [4][NPAD][KPADv], zero-padded.
__global__ void conv_weight(const float* __restrict__ src, f16* __restrict__ dst,
                            int K, int KPADv) {
    size_t total = 4ull * NPAD * KPADv;
    for (size_t idx = (size_t)blockIdx.x * blockDim.x + threadIdx.x; idx < total;
         idx += (size_t)gridDim.x * blockDim.x) {
        int kp = (int)(idx % KPADv);
        size_t rest = idx / KPADv;
        int np = (int)(rest % NPAD);
        int g = (int)(rest / NPAD);
        f16 v = (f16)0.0f;
        if (np < HID_ && kp < K) v = (f16)src[(size_t)(g * HID_ + np) * K + kp];
        dst[idx] = v;
    }
}

// enc_in [B][T][D] fp32 -> xbf [T][B][D] f16
__global__ void conv_x(const float* __restrict__ src, f16* __restrict__ dst) {
    size_t total = (size_t)TT * NB * DIN;
    for (size_t idx = (size_t)blockIdx.x * blockDim.x + threadIdx.x; idx < total;
         idx += (size_t)gridDim.x * blockDim.x) {
        int k = (int)(idx % DIN);
        size_t rest = idx / DIN;
        int b = (int)(rest % NB);
        int t = (int)(rest / NB);
        dst[idx] = (f16)src[((size_t)b * TT + t) * DIN + k];
    }
}

// bias_c[4][NPAD] = b_ih + b_hh (zero-padded)
__global__ void conv_bias(const float* __restrict__ bih, const float* __restrict__ bhh,
                          float* __restrict__ dst) {
    int idx = blockIdx.x * blockDim.x + threadIdx.x;
    if (idx < 4 * NPAD) {
        int np = idx & (NPAD - 1);
        int g = idx >> 10;
        float v = 0.0f;
        if (np < HID_) v = bih[g * HID_ + np] + bhh[g * HID_ + np];
        dst[idx] = v;
    }
}

// One (t, layer) step: gates = A1 @ W1^T + A2 @ W2^T + bias; cell update.
// Grid 256 wgs: wg -> (m-tile of 32 batch rows) x (n-tile of 32 h cols).
// 4 waves per wg, wave g computes gate g's 32x32 tile as 2x2 MFMA frags.
__global__ __launch_bounds__(256) void lstm_step(
    const f16* __restrict__ A1, int lda1, const f16* __restrict__ W1, int k1steps, int kpad1,
    const f16* __restrict__ A2, const f16* __restrict__ W2,
    const float* __restrict__ bias,
    float* __restrict__ cbuf,
    f16* __restrict__ hout,
    float* __restrict__ outp) {
    const int bid = blockIdx.x;
    const int m0 = (bid >> 5) << 5;
    const int n0 = (bid & 31) << 5;
    const int g = threadIdx.x >> 6;
    const int lane = threadIdx.x & 63;
    const int r = lane & 15;
    const int ko = (lane >> 4) << 3;

    f32x4 acc00 = {0.f, 0.f, 0.f, 0.f};
    f32x4 acc01 = acc00, acc10 = acc00, acc11 = acc00;

    // pass 1: input contribution
    {
        const f16* a0p = A1 + (size_t)(m0 + r) * lda1 + ko;
        const f16* a1p = a0p + (size_t)16 * lda1;
        const f16* b0p = W1 + ((size_t)g * NPAD + n0 + r) * kpad1 + ko;
        const f16* b1p = b0p + (size_t)16 * kpad1;
#pragma unroll 2
        for (int ks = 0; ks < k1steps; ks++) {
            f16x8 a0 = *(const f16x8*)(a0p + ks * 32);
            f16x8 a1 = *(const f16x8*)(a1p + ks * 32);
            f16x8 b0 = *(const f16x8*)(b0p + ks * 32);
            f16x8 b1 = *(const f16x8*)(b1p + ks * 32);
            acc00 = __builtin_amdgcn_mfma_f32_16x16x32_f16(a0, b0, acc00, 0, 0, 0);
            acc01 = __builtin_amdgcn_mfma_f32_16x16x32_f16(a0, b1, acc01, 0, 0, 0);
            acc10 = __builtin_amdgcn_mfma_f32_16x16x32_f16(a1, b0, acc10, 0, 0, 0);
            acc11 = __builtin_amdgcn_mfma_f32_16x16x32_f16(a1, b1, acc11, 0, 0, 0);
        }
    }
    // pass 2: recurrent contribution (K = KPAD, 32 steps)
    {
        const f16* a0p = A2 + (size_t)(m0 + r) * KPAD + ko;
        const f16* a1p = a0p + (size_t)16 * KPAD;
        const f16* b0p = W2 + ((size_t)g * NPAD + n0 + r) * KPAD + ko;
        const f16* b1p = b0p + (size_t)16 * KPAD;
#pragma unroll 2
        for (int ks = 0; ks < 32; ks++) {
            f16x8 a0 = *(const f16x8*)(a0p + ks * 32);
            f16x8 a1 = *(const f16x8*)(a1p + ks * 32);
            f16x8 b0 = *(const f16x8*)(b0p + ks * 32);
            f16x8 b1 = *(const f16x8*)(b1p + ks * 32);
            acc00 = __builtin_amdgcn_mfma_f32_16x16x32_f16(a0, b0, acc00, 0, 0, 0);
            acc01 = __builtin_amdgcn_mfma_f32_16x16x32_f16(a0, b1, acc01, 0, 0, 0);
            acc10 = __builtin_amdgcn_mfma_f32_16x16x32_f16(a1, b0, acc10, 0, 0, 0);
            acc11 = __builtin_amdgcn_mfma_f32_16x16x32_f16(a1, b1, acc11, 0, 0, 0);
        }
    }

    __shared__ float lds[4][32][32];
    const int rbase = (lane >> 4) << 2;
#pragma unroll
    for (int q = 0; q < 4; q++) {
        lds[g][rbase + q][r] = acc00[q];
        lds[g][rbase + q][16 + r] = acc01[q];
        lds[g][16 + rbase + q][r] = acc10[q];
        lds[g][16 + rbase + q][16 + r] = acc11[q];
    }
    __syncthreads();

    const int rr = threadIdx.x >> 3;
    const int cc0 = (threadIdx.x & 7) << 2;
    const int b = m0 + rr;
#pragma unroll
    for (int q = 0; q < 4; q++) {
        int cc = cc0 + q;
        int j = n0 + cc;
        if (j < HID_) {
            float ig = lds[0][rr][cc] + bias[0 * NPAD + j];
            float fg = lds[1][rr][cc] + bias[1 * NPAD + j];
            float gg = lds[2][rr][cc] + bias[2 * NPAD + j];
            float og = lds[3][rr][cc] + bias[3 * NPAD + j];
            size_t cidx = (size_t)b * HID_ + j;
            float cold = cbuf[cidx];
            float cn = sigmf_(fg) * cold + sigmf_(ig) * tanhf_(gg);
            float hn = sigmf_(og) * tanhf_(cn);
            cbuf[cidx] = cn;
            hout[(size_t)b * KPAD + j] = (f16)hn;
            outp[(size_t)b * TT * HID_ + j] = hn;
        }
    }
}

extern "C" void kernel_launch(void* const* d_in, const int* in_sizes, int n_in,
                              void* d_out, int out_size, void* d_ws, size_t ws_size,
                              hipStream_t stream) {
    const float* enc_in = (const float*)d_in[0];
    const float* W_ih[3] = {(const float*)d_in[1], (const float*)d_in[5], (const float*)d_in[9]};
    const float* W_hh[3] = {(const float*)d_in[2], (const float*)d_in[6], (const float*)d_in[10]};
    const float* b_ih[3] = {(const float*)d_in[3], (const float*)d_in[7], (const float*)d_in[11]};
    const float* b_hh[3] = {(const float*)d_in[4], (const float*)d_in[8], (const float*)d_in[12]};
    float* out = (float*)d_out;

    char* ws = (char*)d_ws;
    size_t off = 0;
    auto alloc = [&](size_t bytes) {
        char* p = ws + off;
        off += (bytes + 255) & ~(size_t)255;
        return p;
    };
    f16* Wih_c[3];
    f16* Whh_c[3];
    Wih_c[0] = (f16*)alloc(4ull * NPAD * DIN * sizeof(f16));
    Whh_c[0] = (f16*)alloc(4ull * NPAD * KPAD * sizeof(f16));
    Wih_c[1] = (f16*)alloc(4ull * NPAD * KPAD * sizeof(f16));
    Whh_c[1] = (f16*)alloc(4ull * NPAD * KPAD * sizeof(f16));
    Wih_c[2] = (f16*)alloc(4ull * NPAD * KPAD * sizeof(f16));
    Whh_c[2] = (f16*)alloc(4ull * NPAD * KPAD * sizeof(f16));
    float* bias_c[3];
    for (int l = 0; l < 3; l++) bias_c[l] = (float*)alloc(4ull * NPAD * sizeof(float));
    f16* xbf = (f16*)alloc((size_t)TT * NB * DIN * sizeof(f16));
    f16* hbuf = (f16*)alloc(3ull * 2 * NB * KPAD * sizeof(f16));  // [l][parity][NB][KPAD]
    float* cbuf = (float*)alloc(3ull * NB * HID_ * sizeof(float));
    char* state_end = ws + off;

    // zero h (f16) + c (fp32) state in one shot
    hipMemsetAsync(hbuf, 0, (size_t)(state_end - (char*)hbuf), stream);

    conv_weight<<<512, 256, 0, stream>>>(W_ih[0], Wih_c[0], DIN, DIN);
    conv_weight<<<2048, 256, 0, stream>>>(W_hh[0], Whh_c[0], HID_, KPAD);
    conv_weight<<<2048, 256, 0, stream>>>(W_ih[1], Wih_c[1], HID_, KPAD);
    conv_weight<<<2048, 256, 0, stream>>>(W_hh[1], Whh_c[1], HID_, KPAD);
    conv_weight<<<2048, 256, 0, stream>>>(W_ih[2], Wih_c[2], HID_, KPAD);
    conv_weight<<<2048, 256, 0, stream>>>(W_hh[2], Whh_c[2], HID_, KPAD);
    conv_x<<<1024, 256, 0, stream>>>(enc_in, xbf);
    for (int l = 0; l < 3; l++)
        conv_bias<<<(4 * NPAD + 255) / 256, 256, 0, stream>>>(b_ih[l], b_hh[l], bias_c[l]);

    for (int t = 0; t < TT; t++) {
        int pr = t & 1;
        int pw = pr ^ 1;
        for (int l = 0; l < 3; l++) {
            const f16* A1;
            int lda1, k1, kp1;
            const f16* W1c;
            if (l == 0) {
                A1 = xbf + (size_t)t * NB * DIN;
                lda1 = DIN; k1 = DIN / 32; kp1 = DIN;
                W1c = Wih_c[0];
            } else {
                A1 = hbuf + ((size_t)(l - 1) * 2 + pw) * NB * KPAD;
                lda1 = KPAD; k1 = KPAD / 32; kp1 = KPAD;
                W1c = Wih_c[l];
            }
            const f16* A2 = hbuf + ((size_t)l * 2 + pr) * NB * KPAD;
            f16* hout = hbuf + ((size_t)l * 2 + pw) * NB * KPAD;
            float* outp = out + (size_t)l * NB * TT * HID_ + (size_t)t * HID_;
            lstm_step<<<256, 256, 0, stream>>>(A1, lda1, W1c, k1, kp1, A2, Whh_c[l],
                                               bias_c[l], cbuf + (size_t)l * NB * HID_,
                                               hout, outp);
        }
    }
}

// Round 2
// 4704.473 us; speedup vs baseline: 1.0118x; 1.0118x over previous
//
#include <hip/hip_runtime.h>

#define HID_ 1000
#define NB 256
#define TT 49
#define DIN 192
#define NPAD 1024
#define M_ALL (TT * NB)  // 12544

typedef _Float16 f16;
typedef _Float16 f16x2 __attribute__((ext_vector_type(2)));
typedef _Float16 f16x8 __attribute__((ext_vector_type(8)));
typedef float f32x4 __attribute__((ext_vector_type(4)));

__device__ __forceinline__ float sigmf_(float x) {
    return 1.0f / (1.0f + __expf(-x));
}
__device__ __forceinline__ float tanhf_(float x) {
    float ax = fabsf(x);
    float e = __expf(-2.0f * ax);
    float t = (1.0f - e) / (1.0f + e);
    return copysignf(t, x);
}

// Convert fp32 weight [4*HID_][K] -> f16 [4][NPAD][KPADv], zero-padded.
__global__ void conv_weight(const float* __restrict__ src, f16* __restrict__ dst,
                            int K, int KPADv) {
    size_t total = 4ull * NPAD * KPADv;
    for (size_t idx = (size_t)blockIdx.x * blockDim.x + threadIdx.x; idx < total;
         idx += (size_t)gridDim.x * blockDim.x) {
        int kp = (int)(idx % KPADv);
        size_t rest = idx / KPADv;
        int np = (int)(rest % NPAD);
        int g = (int)(rest / NPAD);
        f16 v = (f16)0.0f;
        if (np < HID_ && kp < K) v = (f16)src[(size_t)(g * HID_ + np) * K + kp];
        dst[idx] = v;
    }
}

// enc_in [B][T][D] fp32 -> xbf [T][B][D] f16
__global__ void conv_x(const float* __restrict__ src, f16* __restrict__ dst) {
    size_t total = (size_t)TT * NB * DIN;
    for (size_t idx = (size_t)blockIdx.x * blockDim.x + threadIdx.x; idx < total;
         idx += (size_t)gridDim.x * blockDim.x) {
        int k = (int)(idx % DIN);
        size_t rest = idx / DIN;
        int b = (int)(rest % NB);
        int t = (int)(rest / NB);
        dst[idx] = (f16)src[((size_t)b * TT + t) * DIN + k];
    }
}

// bias_c[4][NPAD] fp32 = b_ih + b_hh (zero-padded)
__global__ void conv_bias(const float* __restrict__ bih, const float* __restrict__ bhh,
                          float* __restrict__ dst) {
    int idx = blockIdx.x * blockDim.x + threadIdx.x;
    if (idx < 4 * NPAD) {
        int np = idx & (NPAD - 1);
        int g = idx >> 10;
        float v = 0.0f;
        if (np < HID_) v = bih[g * HID_ + np] + bhh[g * HID_ + np];
        dst[idx] = v;
    }
}

// pre = A @ W^T + bias.  A [M_ALL][lda] f16, W [4096][ldw] f16, pre [M_ALL][4096] fp32.
// wg = 128x128 tile, 4 waves each 64x64 (4x4 frags). grid = (M_ALL/128)*(4096/128) = 3136.
__global__ __launch_bounds__(256) void input_gemm(
    const f16* __restrict__ A, int lda, int ksteps,
    const f16* __restrict__ W, int ldw,
    const float* __restrict__ bias,
    float* __restrict__ pre) {
    const int bid = blockIdx.x;
    const int n0 = (bid & 31) << 7;
    const int m0 = (bid >> 5) << 7;
    const int w = threadIdx.x >> 6;
    const int lane = threadIdx.x & 63;
    const int r = lane & 15;
    const int ko = (lane >> 4) << 3;
    const int mb = m0 + ((w >> 1) << 6);
    const int nb = n0 + ((w & 1) << 6);

    f32x4 acc[4][4];
#pragma unroll
    for (int i = 0; i < 4; i++)
#pragma unroll
        for (int j = 0; j < 4; j++) acc[i][j] = (f32x4){0.f, 0.f, 0.f, 0.f};

    const f16* ap = A + (size_t)(mb + r) * lda + ko;
    const f16* bp = W + (size_t)(nb + r) * ldw + ko;
#pragma unroll 2
    for (int ks = 0; ks < ksteps; ks++) {
        f16x8 av[4], bv[4];
#pragma unroll
        for (int i = 0; i < 4; i++) av[i] = *(const f16x8*)(ap + (size_t)(i * 16) * lda + ks * 32);
#pragma unroll
        for (int j = 0; j < 4; j++) bv[j] = *(const f16x8*)(bp + (size_t)(j * 16) * ldw + ks * 32);
#pragma unroll
        for (int i = 0; i < 4; i++)
#pragma unroll
            for (int j = 0; j < 4; j++)
                acc[i][j] = __builtin_amdgcn_mfma_f32_16x16x32_f16(av[i], bv[j], acc[i][j], 0, 0, 0);
    }

    const int rbase = (lane >> 4) << 2;
#pragma unroll
    for (int i = 0; i < 4; i++) {
#pragma unroll
        for (int j = 0; j < 4; j++) {
            int col = nb + j * 16 + r;
            float bv = bias[col];
            float* prow = pre + (size_t)(mb + i * 16 + rbase) * 4096 + col;
#pragma unroll
            for (int q = 0; q < 4; q++) prow[(size_t)q * 4096] = acc[i][j][q] + bv;
        }
    }
}

// One recurrent step: gates = pre[t] + h_prev @ W_hh^T; cell update; write h/c/out.
// wg = 32 batch x 16 j-cols, 4 waves (wave g = gate g, 2x1 frags, C-in from pre).
// grid = 8 m-tiles * 64 j-tiles = 512 wgs.
__global__ __launch_bounds__(256) void rec_step(
    const f16* __restrict__ hprev,
    const f16* __restrict__ Whh,
    const float* __restrict__ pre_t,
    float* __restrict__ cbuf,
    f16* __restrict__ hnew,
    f16* __restrict__ hall_t,
    float* __restrict__ out_t) {
    const int bid = blockIdx.x;
    const int m0 = (bid >> 6) << 5;
    const int j0 = (bid & 63) << 4;
    const int g = threadIdx.x >> 6;
    const int lane = threadIdx.x & 63;
    const int r = lane & 15;
    const int ko = (lane >> 4) << 3;
    const int rbase = (lane >> 4) << 2;

    // init accumulators from pre (C-in)
    f32x4 acc0, acc1;
    {
        const float* p0 = pre_t + (size_t)(m0 + rbase) * 4096 + g * NPAD + j0 + r;
#pragma unroll
        for (int q = 0; q < 4; q++) acc0[q] = p0[(size_t)q * 4096];
        const float* p1 = p0 + (size_t)16 * 4096;
#pragma unroll
        for (int q = 0; q < 4; q++) acc1[q] = p1[(size_t)q * 4096];
    }

    const f16* ap = hprev + (size_t)(m0 + r) * NPAD + ko;
    const f16* bp = Whh + (size_t)(g * NPAD + j0 + r) * NPAD + ko;
#pragma unroll 4
    for (int ks = 0; ks < 32; ks++) {
        f16x8 a0 = *(const f16x8*)(ap + ks * 32);
        f16x8 a1 = *(const f16x8*)(ap + (size_t)16 * NPAD + ks * 32);
        f16x8 b0 = *(const f16x8*)(bp + ks * 32);
        acc0 = __builtin_amdgcn_mfma_f32_16x16x32_f16(a0, b0, acc0, 0, 0, 0);
        acc1 = __builtin_amdgcn_mfma_f32_16x16x32_f16(a1, b0, acc1, 0, 0, 0);
    }

    __shared__ float lds[4][32][16];
#pragma unroll
    for (int q = 0; q < 4; q++) {
        lds[g][rbase + q][r] = acc0[q];
        lds[g][16 + rbase + q][r] = acc1[q];
    }
    __syncthreads();

    const int rr = threadIdx.x >> 3;
    const int cc = (threadIdx.x & 7) << 1;
    const int b = m0 + rr;
    const int j = j0 + cc;

    float hv[2], cv[2];
#pragma unroll
    for (int q = 0; q < 2; q++) {
        float ig = lds[0][rr][cc + q];
        float fg = lds[1][rr][cc + q];
        float gg = lds[2][rr][cc + q];
        float og = lds[3][rr][cc + q];
        float cold = cbuf[(size_t)b * NPAD + j + q];
        float cn = sigmf_(fg) * cold + sigmf_(ig) * tanhf_(gg);
        hv[q] = sigmf_(og) * tanhf_(cn);
        cv[q] = cn;
    }
    *(float2*)(cbuf + (size_t)b * NPAD + j) = make_float2(cv[0], cv[1]);
    f16x2 hp;
    hp[0] = (f16)hv[0];
    hp[1] = (f16)hv[1];
    *(f16x2*)(hnew + (size_t)b * NPAD + j) = hp;
    *(f16x2*)(hall_t + (size_t)b * NPAD + j) = hp;
    if (j < HID_) *(float2*)(out_t + (size_t)b * TT * HID_ + j) = make_float2(hv[0], hv[1]);
}

extern "C" void kernel_launch(void* const* d_in, const int* in_sizes, int n_in,
                              void* d_out, int out_size, void* d_ws, size_t ws_size,
                              hipStream_t stream) {
    const float* enc_in = (const float*)d_in[0];
    const float* W_ih[3] = {(const float*)d_in[1], (const float*)d_in[5], (const float*)d_in[9]};
    const float* W_hh[3] = {(const float*)d_in[2], (const float*)d_in[6], (const float*)d_in[10]};
    const float* b_ih[3] = {(const float*)d_in[3], (const float*)d_in[7], (const float*)d_in[11]};
    const float* b_hh[3] = {(const float*)d_in[4], (const float*)d_in[8], (const float*)d_in[12]};
    float* out = (float*)d_out;

    char* ws = (char*)d_ws;
    size_t off = 0;
    auto alloc = [&](size_t bytes) {
        char* p = ws + off;
        off += (bytes + 255) & ~(size_t)255;
        return p;
    };
    f16* Wih_c[3];
    f16* Whh_c[3];
    Wih_c[0] = (f16*)alloc(4ull * NPAD * DIN * sizeof(f16));
    Whh_c[0] = (f16*)alloc(4ull * NPAD * NPAD * sizeof(f16));
    Wih_c[1] = (f16*)alloc(4ull * NPAD * NPAD * sizeof(f16));
    Whh_c[1] = (f16*)alloc(4ull * NPAD * NPAD * sizeof(f16));
    Wih_c[2] = (f16*)alloc(4ull * NPAD * NPAD * sizeof(f16));
    Whh_c[2] = (f16*)alloc(4ull * NPAD * NPAD * sizeof(f16));
    float* bias_c[3];
    for (int l = 0; l < 3; l++) bias_c[l] = (float*)alloc(4ull * NPAD * sizeof(float));
    f16* xbf = (f16*)alloc((size_t)TT * NB * DIN * sizeof(f16));
    f16* hall[3];
    for (int l = 0; l < 3; l++) hall[l] = (f16*)alloc((size_t)TT * NB * NPAD * sizeof(f16));
    float* pre = (float*)alloc((size_t)M_ALL * 4096 * sizeof(float));
    // per-layer state (zeroed each layer): hcurA, hcurB, cbuf — contiguous
    f16* hcurA = (f16*)alloc((size_t)NB * NPAD * sizeof(f16));
    f16* hcurB = (f16*)alloc((size_t)NB * NPAD * sizeof(f16));
    float* cbuf = (float*)alloc((size_t)NB * NPAD * sizeof(float));
    size_t state_bytes = (size_t)NB * NPAD * (2 * sizeof(f16) + sizeof(float));

    conv_weight<<<512, 256, 0, stream>>>(W_ih[0], Wih_c[0], DIN, DIN);
    conv_weight<<<2048, 256, 0, stream>>>(W_hh[0], Whh_c[0], HID_, NPAD);
    conv_weight<<<2048, 256, 0, stream>>>(W_ih[1], Wih_c[1], HID_, NPAD);
    conv_weight<<<2048, 256, 0, stream>>>(W_hh[1], Whh_c[1], HID_, NPAD);
    conv_weight<<<2048, 256, 0, stream>>>(W_ih[2], Wih_c[2], HID_, NPAD);
    conv_weight<<<2048, 256, 0, stream>>>(W_hh[2], Whh_c[2], HID_, NPAD);
    conv_x<<<1024, 256, 0, stream>>>(enc_in, xbf);
    for (int l = 0; l < 3; l++)
        conv_bias<<<(4 * NPAD + 255) / 256, 256, 0, stream>>>(b_ih[l], b_hh[l], bias_c[l]);

    for (int l = 0; l < 3; l++) {
        hipMemsetAsync(hcurA, 0, state_bytes, stream);
        if (l == 0)
            input_gemm<<<3136, 256, 0, stream>>>(xbf, DIN, DIN / 32, Wih_c[0], DIN,
                                                 bias_c[0], pre);
        else
            input_gemm<<<3136, 256, 0, stream>>>(hall[l - 1], NPAD, NPAD / 32, Wih_c[l], NPAD,
                                                 bias_c[l], pre);
        for (int t = 0; t < TT; t++) {
            const f16* hp = (t & 1) ? hcurB : hcurA;
            f16* hn = (t & 1) ? hcurA : hcurB;
            rec_step<<<512, 256, 0, stream>>>(
                hp, Whh_c[l], pre + (size_t)t * NB * 4096, cbuf, hn,
                hall[l] + (size_t)t * NB * NPAD,
                out + (size_t)l * NB * TT * HID_ + (size_t)t * HID_);
        }
    }
}

// Round 4
// 3918.494 us; speedup vs baseline: 1.2147x; 1.2006x over previous
//
#include <hip/hip_runtime.h>

#define HID_ 1000
#define NB 256
#define TT 49
#define DIN 192
#define NPAD 1024
#define M_ALL (TT * NB)  // 12544

typedef _Float16 f16;
typedef _Float16 f16x4 __attribute__((ext_vector_type(4)));
typedef _Float16 f16x8 __attribute__((ext_vector_type(8)));
typedef float f32x4 __attribute__((ext_vector_type(4)));
typedef const __attribute__((address_space(1))) unsigned int* gas_u32;
typedef __attribute__((address_space(3))) unsigned int* las_u32;

__device__ __forceinline__ float sigmf_(float x) {
    return 1.0f / (1.0f + __expf(-x));
}
__device__ __forceinline__ float tanhf_(float x) {
    float ax = fabsf(x);
    float e = __expf(-2.0f * ax);
    float t = (1.0f - e) / (1.0f + e);
    return copysignf(t, x);
}

// Convert fp32 weight [4*HID_][K] -> f16 [4][NPAD][KPADv], zero-padded.
__global__ void conv_weight(const float* __restrict__ src, f16* __restrict__ dst,
                            int K, int KPADv) {
    size_t total = 4ull * NPAD * KPADv;
    for (size_t idx = (size_t)blockIdx.x * blockDim.x + threadIdx.x; idx < total;
         idx += (size_t)gridDim.x * blockDim.x) {
        int kp = (int)(idx % KPADv);
        size_t rest = idx / KPADv;
        int np = (int)(rest % NPAD);
        int g = (int)(rest / NPAD);
        f16 v = (f16)0.0f;
        if (np < HID_ && kp < K) v = (f16)src[(size_t)(g * HID_ + np) * K + kp];
        dst[idx] = v;
    }
}

// enc_in [B][T][D] fp32 -> xbf [T][B][D] f16
__global__ void conv_x(const float* __restrict__ src, f16* __restrict__ dst) {
    size_t total = (size_t)TT * NB * DIN;
    for (size_t idx = (size_t)blockIdx.x * blockDim.x + threadIdx.x; idx < total;
         idx += (size_t)gridDim.x * blockDim.x) {
        int k = (int)(idx % DIN);
        size_t rest = idx / DIN;
        int b = (int)(rest % NB);
        int t = (int)(rest / NB);
        dst[idx] = (f16)src[((size_t)b * TT + t) * DIN + k];
    }
}

// bias_c[4][NPAD] fp32 = b_ih + b_hh (zero-padded)
__global__ void conv_bias(const float* __restrict__ bih, const float* __restrict__ bhh,
                          float* __restrict__ dst) {
    int idx = blockIdx.x * blockDim.x + threadIdx.x;
    if (idx < 4 * NPAD) {
        int np = idx & (NPAD - 1);
        int g = idx >> 10;
        float v = 0.0f;
        if (np < HID_) v = bih[g * HID_ + np] + bhh[g * HID_ + np];
        dst[idx] = v;
    }
}

// pre = A @ W^T + bias (f16 out). m97 structure: 128x128 tile, BK=64,
// global_load_lds staging, 2-barrier loop. grid = 98*32 = 3136 (XCD-swizzled).
__global__ __launch_bounds__(256) void input_gemm(
    const f16* __restrict__ A, int lda, int kiters,
    const f16* __restrict__ W, int ldw,
    const float* __restrict__ bias,
    f16* __restrict__ pre) {
    __shared__ f16 As[128 * 64];
    __shared__ f16 Bs[128 * 64];
    const int id = blockIdx.x;
    const int sw = (id & 7) * (gridDim.x >> 3) + (id >> 3);  // XCD swizzle (3136%8==0)
    const int m0 = (sw >> 5) << 7;
    const int n0 = (sw & 31) << 7;
    const int w = threadIdx.x >> 6;
    const int lane = threadIdx.x & 63;
    const int r = lane & 15;
    const int kb8 = (lane >> 4) << 3;  // frag k-offset (elements)
    const int wm = (w >> 1) << 6, wn = (w & 1) << 6;
    const int strow = (w << 5) + (lane >> 3);  // + q*8
    const int stcol = (lane & 7) << 3;         // elements

    f32x4 acc[4][4];
#pragma unroll
    for (int i = 0; i < 4; i++)
#pragma unroll
        for (int j = 0; j < 4; j++) acc[i][j] = (f32x4){0.f, 0.f, 0.f, 0.f};

    for (int kt = 0; kt < kiters; kt++) {
        const int k0 = kt << 6;
#pragma unroll
        for (int q = 0; q < 4; q++) {
            const int row = strow + (q << 3);
            const int cbase = ((w << 5) + (q << 3)) << 6;  // wave-uniform chunk base (elems)
            const f16* ga = A + (size_t)(m0 + row) * lda + k0 + stcol;
            const f16* gb = W + (size_t)(n0 + row) * ldw + k0 + stcol;
            __builtin_amdgcn_global_load_lds((gas_u32)ga, (las_u32)(As + cbase), 16, 0, 0);
            __builtin_amdgcn_global_load_lds((gas_u32)gb, (las_u32)(Bs + cbase), 16, 0, 0);
        }
        __syncthreads();
#pragma unroll
        for (int ks = 0; ks < 2; ks++) {
            f16x8 av[4], bv[4];
#pragma unroll
            for (int i = 0; i < 4; i++)
                av[i] = *(const f16x8*)(As + ((wm + i * 16 + r) << 6) + (ks << 5) + kb8);
#pragma unroll
            for (int j = 0; j < 4; j++)
                bv[j] = *(const f16x8*)(Bs + ((wn + j * 16 + r) << 6) + (ks << 5) + kb8);
#pragma unroll
            for (int i = 0; i < 4; i++)
#pragma unroll
                for (int j = 0; j < 4; j++)
                    acc[i][j] = __builtin_amdgcn_mfma_f32_16x16x32_f16(av[i], bv[j], acc[i][j], 0, 0, 0);
        }
        __syncthreads();
    }

    const int rbase = (lane >> 4) << 2;
#pragma unroll
    for (int j = 0; j < 4; j++) {
        const int col = n0 + wn + j * 16 + r;
        const float bj = bias[col];
#pragma unroll
        for (int i = 0; i < 4; i++) {
            f16* prow = pre + (size_t)(m0 + wm + i * 16 + rbase) * 4096 + col;
#pragma unroll
            for (int q = 0; q < 4; q++) prow[(size_t)q * 4096] = (f16)(acc[i][j][q] + bj);
        }
    }
}

// Persistent per-layer recurrent kernel. grid = 256 wgs x 256 thr (normal launch:
// 256 wgs, each needs >=1/CU of resources on 256 CUs -> all co-resident).
// wg (bt,jt): batches [bt*32,+32), cols [jt*32,+32) x 4 gates. Weights in VGPRs
// (wave g = gate g, 2 n-frags x 32 k-steps = 256 VGPR). c-state in registers.
// Group barrier: flags[bt*TT+t] counts arrivals of the 32 jt-wgs of group bt.
__global__ __launch_bounds__(256, 1) void rec_persist(
    const f16* __restrict__ Whh, const f16* __restrict__ pre,
    f16* __restrict__ hall, float* __restrict__ outl,
    f16* __restrict__ h0, f16* __restrict__ h1,
    unsigned int* __restrict__ flags) {
    __shared__ __align__(16) char smem[64 * 1024];  // h tile [32][2048B] swizzled; gates alias
    float* gl = (float*)smem;                       // [4][32][32] f32 (after h reads done)
    const int bid = blockIdx.x;
    const int bt = bid >> 5;
    const int jt = bid & 31;
    const int b0 = bt << 5;
    const int jc0 = jt << 5;
    const int tid = threadIdx.x;
    const int g = tid >> 6;
    const int lane = tid & 63;
    const int r = lane & 15;
    const int kb8 = (lane >> 4) << 3;  // elements
    const int kbb = kb8 << 1;          // bytes
    const int rbase = (lane >> 4) << 2;
    const int swz = (r & 7) << 4;

    // load weights into registers (once per layer)
    f16x8 wreg[2][32];
#pragma unroll
    for (int n = 0; n < 2; n++) {
        const f16* wp = Whh + ((size_t)(g * NPAD + jc0 + n * 16 + r)) * NPAD + kb8;
#pragma unroll
        for (int ks = 0; ks < 32; ks++) wreg[n][ks] = *(const f16x8*)(wp + ks * 32);
    }

    const int eb = tid >> 3;         // epilogue batch row 0..31
    const int ej = (tid & 7) << 2;   // epilogue col 0..28
    float cv[4] = {0.f, 0.f, 0.f, 0.f};
    unsigned int* myflags = flags + bt * TT;

    for (int t = 0; t < TT; t++) {
        const f16* hread = (t & 1) ? h0 : h1;
        f16* hw = ((t + 1) & 1) ? h0 : h1;  // write buffer opposite to next read

        // acc init from pre (C-in) — independent of h, do before the flag wait
        f32x4 acc[2][2];
        {
            const f16* pp = pre + ((size_t)t * NB + b0) * 4096 + (g << 10) + jc0;
#pragma unroll
            for (int mi = 0; mi < 2; mi++)
#pragma unroll
                for (int n = 0; n < 2; n++)
#pragma unroll
                    for (int q = 0; q < 4; q++)
                        acc[mi][n][q] = (float)pp[(size_t)(mi * 16 + rbase + q) * 4096 + n * 16 + r];
        }

        if (t > 0) {
            if (tid == 0) {
                while (__hip_atomic_load(myflags + (t - 1), __ATOMIC_ACQUIRE,
                                         __HIP_MEMORY_SCOPE_AGENT) < 32u) {}
            }
            __syncthreads();
            (void)__hip_atomic_load(myflags + (t - 1), __ATOMIC_ACQUIRE,
                                    __HIP_MEMORY_SCOPE_AGENT);  // L1 invalidate for this wave
            // stage h[b0..+32][1024] -> LDS (XOR-swizzled rows)
#pragma unroll
            for (int i = 0; i < 16; i++) {
                int c = tid + (i << 8);
                int row = c >> 7;
                int cb = (c & 127) << 4;
                f16x8 v = *(const f16x8*)(hread + (size_t)(b0 + row) * NPAD + (cb >> 1));
                *(f16x8*)(smem + row * 2048 + (cb ^ ((row & 7) << 4))) = v;
            }
            __syncthreads();
#pragma unroll
            for (int ks = 0; ks < 32; ks++) {
                f16x8 a0 = *(const f16x8*)(smem + r * 2048 + ((ks * 64 + kbb) ^ swz));
                f16x8 a1 = *(const f16x8*)(smem + (16 + r) * 2048 + ((ks * 64 + kbb) ^ swz));
                acc[0][0] = __builtin_amdgcn_mfma_f32_16x16x32_f16(a0, wreg[0][ks], acc[0][0], 0, 0, 0);
                acc[0][1] = __builtin_amdgcn_mfma_f32_16x16x32_f16(a0, wreg[1][ks], acc[0][1], 0, 0, 0);
                acc[1][0] = __builtin_amdgcn_mfma_f32_16x16x32_f16(a1, wreg[0][ks], acc[1][0], 0, 0, 0);
                acc[1][1] = __builtin_amdgcn_mfma_f32_16x16x32_f16(a1, wreg[1][ks], acc[1][1], 0, 0, 0);
            }
        }
        __syncthreads();  // all h-LDS reads done before gates alias it

        // gates -> LDS
#pragma unroll
        for (int mi = 0; mi < 2; mi++)
#pragma unroll
            for (int n = 0; n < 2; n++)
#pragma unroll
                for (int q = 0; q < 4; q++)
                    gl[(g * 32 + mi * 16 + rbase + q) * 32 + n * 16 + r] = acc[mi][n][q];
        __syncthreads();

        // cell update: thread -> (eb, ej..ej+3)
        float hvv[4];
#pragma unroll
        for (int q = 0; q < 4; q++) {
            float i_ = gl[(0 * 32 + eb) * 32 + ej + q];
            float f_ = gl[(1 * 32 + eb) * 32 + ej + q];
            float g_ = gl[(2 * 32 + eb) * 32 + ej + q];
            float o_ = gl[(3 * 32 + eb) * 32 + ej + q];
            float cn = sigmf_(f_) * cv[q] + sigmf_(i_) * tanhf_(g_);
            hvv[q] = sigmf_(o_) * tanhf_(cn);
            cv[q] = cn;
        }
        f16x4 hh;
#pragma unroll
        for (int q = 0; q < 4; q++) hh[q] = (f16)hvv[q];
        *(f16x4*)(hw + (size_t)(b0 + eb) * NPAD + jc0 + ej) = hh;
        *(f16x4*)(hall + ((size_t)t * NB + b0 + eb) * NPAD + jc0 + ej) = hh;
        const int col = jc0 + ej;
        if (col < HID_) {
            float4 o4 = make_float4(hvv[0], hvv[1], hvv[2], hvv[3]);
            *(float4*)(outl + ((size_t)(b0 + eb) * TT + t) * HID_ + col) = o4;
        }
        __syncthreads();  // gl reads done before next step's h stage overwrites
        if (tid == 0)
            __hip_atomic_fetch_add(myflags + t, 1u, __ATOMIC_RELEASE, __HIP_MEMORY_SCOPE_AGENT);
    }
}

extern "C" void kernel_launch(void* const* d_in, const int* in_sizes, int n_in,
                              void* d_out, int out_size, void* d_ws, size_t ws_size,
                              hipStream_t stream) {
    const float* enc_in = (const float*)d_in[0];
    const float* W_ih[3] = {(const float*)d_in[1], (const float*)d_in[5], (const float*)d_in[9]};
    const float* W_hh[3] = {(const float*)d_in[2], (const float*)d_in[6], (const float*)d_in[10]};
    const float* b_ih[3] = {(const float*)d_in[3], (const float*)d_in[7], (const float*)d_in[11]};
    const float* b_hh[3] = {(const float*)d_in[4], (const float*)d_in[8], (const float*)d_in[12]};
    float* out = (float*)d_out;

    char* ws = (char*)d_ws;
    size_t off = 0;
    auto alloc = [&](size_t bytes) {
        char* p = ws + off;
        off += (bytes + 255) & ~(size_t)255;
        return p;
    };
    f16* Wih_c[3];
    f16* Whh_c[3];
    Wih_c[0] = (f16*)alloc(4ull * NPAD * DIN * sizeof(f16));
    Whh_c[0] = (f16*)alloc(4ull * NPAD * NPAD * sizeof(f16));
    Wih_c[1] = (f16*)alloc(4ull * NPAD * NPAD * sizeof(f16));
    Whh_c[1] = (f16*)alloc(4ull * NPAD * NPAD * sizeof(f16));
    Wih_c[2] = (f16*)alloc(4ull * NPAD * NPAD * sizeof(f16));
    Whh_c[2] = (f16*)alloc(4ull * NPAD * NPAD * sizeof(f16));
    float* bias_c[3];
    for (int l = 0; l < 3; l++) bias_c[l] = (float*)alloc(4ull * NPAD * sizeof(float));
    f16* xbf = (f16*)alloc((size_t)TT * NB * DIN * sizeof(f16));
    f16* hall[3];
    for (int l = 0; l < 3; l++) hall[l] = (f16*)alloc((size_t)TT * NB * NPAD * sizeof(f16));
    f16* pre = (f16*)alloc((size_t)M_ALL * 4096 * sizeof(f16));
    f16* h0 = (f16*)alloc((size_t)NB * NPAD * sizeof(f16));
    f16* h1 = (f16*)alloc((size_t)NB * NPAD * sizeof(f16));
    unsigned int* flags = (unsigned int*)alloc(3ull * 8 * TT * sizeof(unsigned int));

    hipMemsetAsync(flags, 0, 3ull * 8 * TT * sizeof(unsigned int), stream);

    conv_weight<<<512, 256, 0, stream>>>(W_ih[0], Wih_c[0], DIN, DIN);
    conv_weight<<<2048, 256, 0, stream>>>(W_hh[0], Whh_c[0], HID_, NPAD);
    conv_weight<<<2048, 256, 0, stream>>>(W_ih[1], Wih_c[1], HID_, NPAD);
    conv_weight<<<2048, 256, 0, stream>>>(W_hh[1], Whh_c[1], HID_, NPAD);
    conv_weight<<<2048, 256, 0, stream>>>(W_ih[2], Wih_c[2], HID_, NPAD);
    conv_weight<<<2048, 256, 0, stream>>>(W_hh[2], Whh_c[2], HID_, NPAD);
    conv_x<<<1024, 256, 0, stream>>>(enc_in, xbf);
    for (int l = 0; l < 3; l++)
        conv_bias<<<(4 * NPAD + 255) / 256, 256, 0, stream>>>(b_ih[l], b_hh[l], bias_c[l]);

    for (int l = 0; l < 3; l++) {
        if (l == 0)
            input_gemm<<<3136, 256, 0, stream>>>(xbf, DIN, DIN / 64, Wih_c[0], DIN,
                                                 bias_c[0], pre);
        else
            input_gemm<<<3136, 256, 0, stream>>>(hall[l - 1], NPAD, NPAD / 64, Wih_c[l], NPAD,
                                                 bias_c[l], pre);
        rec_persist<<<256, 256, 0, stream>>>(
            Whh_c[l], pre, hall[l], out + (size_t)l * NB * TT * HID_, h0, h1,
            flags + (size_t)l * 8 * TT);
    }
}

// Round 5
// 1744.667 us; speedup vs baseline: 2.7282x; 2.2460x over previous
//
#include <hip/hip_runtime.h>

#define HID_ 1000
#define NB 256
#define TT 49
#define DIN 192
#define NPAD 1024
#define M_ALL (TT * NB)  // 12544

typedef _Float16 f16;
typedef _Float16 f16x4 __attribute__((ext_vector_type(4)));
typedef _Float16 f16x8 __attribute__((ext_vector_type(8)));
typedef float f32x4 __attribute__((ext_vector_type(4)));
typedef const __attribute__((address_space(1))) unsigned int* gas_u32;
typedef __attribute__((address_space(3))) unsigned int* las_u32;

__device__ __forceinline__ float sigmf_(float x) {
    return 1.0f / (1.0f + __expf(-x));
}
__device__ __forceinline__ float tanhf_(float x) {
    float ax = fabsf(x);
    float e = __expf(-2.0f * ax);
    float t = (1.0f - e) / (1.0f + e);
    return copysignf(t, x);
}

// Convert fp32 weight [4*HID_][K] -> f16 [4][NPAD][KPADv], zero-padded.
__global__ void conv_weight(const float* __restrict__ src, f16* __restrict__ dst,
                            int K, int KPADv) {
    size_t total = 4ull * NPAD * KPADv;
    for (size_t idx = (size_t)blockIdx.x * blockDim.x + threadIdx.x; idx < total;
         idx += (size_t)gridDim.x * blockDim.x) {
        int kp = (int)(idx % KPADv);
        size_t rest = idx / KPADv;
        int np = (int)(rest % NPAD);
        int g = (int)(rest / NPAD);
        f16 v = (f16)0.0f;
        if (np < HID_ && kp < K) v = (f16)src[(size_t)(g * HID_ + np) * K + kp];
        dst[idx] = v;
    }
}

// enc_in [B][T][D] fp32 -> xbf [T][B][D] f16
__global__ void conv_x(const float* __restrict__ src, f16* __restrict__ dst) {
    size_t total = (size_t)TT * NB * DIN;
    for (size_t idx = (size_t)blockIdx.x * blockDim.x + threadIdx.x; idx < total;
         idx += (size_t)gridDim.x * blockDim.x) {
        int k = (int)(idx % DIN);
        size_t rest = idx / DIN;
        int b = (int)(rest % NB);
        int t = (int)(rest / NB);
        dst[idx] = (f16)src[((size_t)b * TT + t) * DIN + k];
    }
}

// bias_c[4][NPAD] fp32 = b_ih + b_hh (zero-padded)
__global__ void conv_bias(const float* __restrict__ bih, const float* __restrict__ bhh,
                          float* __restrict__ dst) {
    int idx = blockIdx.x * blockDim.x + threadIdx.x;
    if (idx < 4 * NPAD) {
        int np = idx & (NPAD - 1);
        int g = idx >> 10;
        float v = 0.0f;
        if (np < HID_) v = bih[g * HID_ + np] + bhh[g * HID_ + np];
        dst[idx] = v;
    }
}

// pre = A @ W^T + bias (f16 out). m97 structure: 128x128 tile, BK=64,
// global_load_lds staging, 2-barrier loop. grid = 98*32 = 3136 (XCD-swizzled).
__global__ __launch_bounds__(256) void input_gemm(
    const f16* __restrict__ A, int lda, int kiters,
    const f16* __restrict__ W, int ldw,
    const float* __restrict__ bias,
    f16* __restrict__ pre) {
    __shared__ f16 As[128 * 64];
    __shared__ f16 Bs[128 * 64];
    const int id = blockIdx.x;
    const int sw = (id & 7) * (gridDim.x >> 3) + (id >> 3);  // XCD swizzle (3136%8==0)
    const int m0 = (sw >> 5) << 7;
    const int n0 = (sw & 31) << 7;
    const int w = threadIdx.x >> 6;
    const int lane = threadIdx.x & 63;
    const int r = lane & 15;
    const int kb8 = (lane >> 4) << 3;  // frag k-offset (elements)
    const int wm = (w >> 1) << 6, wn = (w & 1) << 6;
    const int strow = (w << 5) + (lane >> 3);  // + q*8
    const int stcol = (lane & 7) << 3;         // elements

    f32x4 acc[4][4];
#pragma unroll
    for (int i = 0; i < 4; i++)
#pragma unroll
        for (int j = 0; j < 4; j++) acc[i][j] = (f32x4){0.f, 0.f, 0.f, 0.f};

    for (int kt = 0; kt < kiters; kt++) {
        const int k0 = kt << 6;
#pragma unroll
        for (int q = 0; q < 4; q++) {
            const int row = strow + (q << 3);
            const int cbase = ((w << 5) + (q << 3)) << 6;  // wave-uniform chunk base (elems)
            const f16* ga = A + (size_t)(m0 + row) * lda + k0 + stcol;
            const f16* gb = W + (size_t)(n0 + row) * ldw + k0 + stcol;
            __builtin_amdgcn_global_load_lds((gas_u32)ga, (las_u32)(As + cbase), 16, 0, 0);
            __builtin_amdgcn_global_load_lds((gas_u32)gb, (las_u32)(Bs + cbase), 16, 0, 0);
        }
        __syncthreads();
#pragma unroll
        for (int ks = 0; ks < 2; ks++) {
            f16x8 av[4], bv[4];
#pragma unroll
            for (int i = 0; i < 4; i++)
                av[i] = *(const f16x8*)(As + ((wm + i * 16 + r) << 6) + (ks << 5) + kb8);
#pragma unroll
            for (int j = 0; j < 4; j++)
                bv[j] = *(const f16x8*)(Bs + ((wn + j * 16 + r) << 6) + (ks << 5) + kb8);
#pragma unroll
            for (int i = 0; i < 4; i++)
#pragma unroll
                for (int j = 0; j < 4; j++)
                    acc[i][j] = __builtin_amdgcn_mfma_f32_16x16x32_f16(av[i], bv[j], acc[i][j], 0, 0, 0);
        }
        __syncthreads();
    }

    const int rbase = (lane >> 4) << 2;
#pragma unroll
    for (int j = 0; j < 4; j++) {
        const int col = n0 + wn + j * 16 + r;
        const float bj = bias[col];
#pragma unroll
        for (int i = 0; i < 4; i++) {
            f16* prow = pre + (size_t)(m0 + wm + i * 16 + rbase) * 4096 + col;
#pragma unroll
            for (int q = 0; q < 4; q++) prow[(size_t)q * 4096] = (f16)(acc[i][j][q] + bj);
        }
    }
}

// Persistent per-layer recurrent kernel. 256 wgs x 256 thr, 1 wg/CU.
// Group bt = bid & 7 (32 wgs; with round-robin dispatch these share one XCD
// -> L2-local h traffic). Correctness does NOT depend on that: h is published
// via relaxed AGENT-scope atomic stores (device coherence point) and read at
// first-touch addresses (hall[t-1], never previously cached this dispatch).
// No acquire/release -> no buffer_inv/wbl2 -> weights stay L2-resident.
__global__ __launch_bounds__(256, 1) void rec_persist(
    const f16* __restrict__ Whh, const f16* __restrict__ pre,
    f16* __restrict__ hall, float* __restrict__ outl,
    unsigned int* __restrict__ flags) {
    __shared__ __align__(16) char smem[64 * 1024];  // h tile [32][2048B] swizzled; gl aliases
    float* gl = (float*)smem;                       // [4][32][33] f32 (after h reads done)
    const int bid = blockIdx.x;
    const int bt = bid & 7;    // group = XCD under round-robin dispatch
    const int jt = bid >> 3;   // 0..31 column tile
    const int b0 = bt << 5;
    const int jc0 = jt << 5;
    const int tid = threadIdx.x;
    const int g = tid >> 6;
    const int lane = tid & 63;
    const int r = lane & 15;
    const int kb8 = (lane >> 4) << 3;  // elements
    const int kbb = kb8 << 1;          // bytes
    const int rbase = (lane >> 4) << 2;
    const int swz = (r & 7) << 4;

    // load weights into registers/AGPRs (once per layer)
    f16x8 wreg[2][32];
#pragma unroll
    for (int n = 0; n < 2; n++) {
        const f16* wp = Whh + ((size_t)(g * NPAD + jc0 + n * 16 + r)) * NPAD + kb8;
#pragma unroll
        for (int ks = 0; ks < 32; ks++) wreg[n][ks] = *(const f16x8*)(wp + ks * 32);
    }

    const int eb = tid >> 3;         // epilogue batch row 0..31
    const int ej = (tid & 7) << 2;   // epilogue col 0..28
    float cv[4] = {0.f, 0.f, 0.f, 0.f};
    unsigned int* myflags = flags + bt * TT;

    for (int t = 0; t < TT; t++) {
        // acc init from pre (C-in) — independent of h, hoisted above the wait
        f32x4 acc[2][2];
        {
            const f16* pp = pre + ((size_t)t * NB + b0) * 4096 + (g << 10) + jc0;
#pragma unroll
            for (int mi = 0; mi < 2; mi++)
#pragma unroll
                for (int n = 0; n < 2; n++)
#pragma unroll
                    for (int q = 0; q < 4; q++)
                        acc[mi][n][q] = (float)pp[(size_t)(mi * 16 + rbase + q) * 4096 + n * 16 + r];
        }

        if (t > 0) {
            if (tid == 0) {
                while (__hip_atomic_load(myflags + (t - 1), __ATOMIC_RELAXED,
                                         __HIP_MEMORY_SCOPE_AGENT) < 32u) {}
            }
            __syncthreads();
            asm volatile("" ::: "memory");
            // stage h = hall[t-1] rows b0..b0+31 -> LDS (XOR-swizzled rows)
            const f16* hread = hall + (size_t)(t - 1) * NB * NPAD;
#pragma unroll
            for (int i = 0; i < 16; i++) {
                int c = tid + (i << 8);
                int row = c >> 7;
                int cb = (c & 127) << 4;
                f16x8 v = *(const f16x8*)(hread + (size_t)(b0 + row) * NPAD + (cb >> 1));
                *(f16x8*)(smem + row * 2048 + (cb ^ ((row & 7) << 4))) = v;
            }
            __syncthreads();
#pragma unroll
            for (int ks = 0; ks < 32; ks++) {
                f16x8 a0 = *(const f16x8*)(smem + r * 2048 + ((ks * 64 + kbb) ^ swz));
                f16x8 a1 = *(const f16x8*)(smem + (16 + r) * 2048 + ((ks * 64 + kbb) ^ swz));
                acc[0][0] = __builtin_amdgcn_mfma_f32_16x16x32_f16(a0, wreg[0][ks], acc[0][0], 0, 0, 0);
                acc[0][1] = __builtin_amdgcn_mfma_f32_16x16x32_f16(a0, wreg[1][ks], acc[0][1], 0, 0, 0);
                acc[1][0] = __builtin_amdgcn_mfma_f32_16x16x32_f16(a1, wreg[0][ks], acc[1][0], 0, 0, 0);
                acc[1][1] = __builtin_amdgcn_mfma_f32_16x16x32_f16(a1, wreg[1][ks], acc[1][1], 0, 0, 0);
            }
        }
        __syncthreads();  // all h-LDS reads done before gl aliases it

        // gates -> LDS (stride 33 kills the 4-way bank conflict)
#pragma unroll
        for (int mi = 0; mi < 2; mi++)
#pragma unroll
            for (int n = 0; n < 2; n++)
#pragma unroll
                for (int q = 0; q < 4; q++)
                    gl[(g * 32 + mi * 16 + rbase + q) * 33 + n * 16 + r] = acc[mi][n][q];
        __syncthreads();

        // cell update: thread -> (eb, ej..ej+3)
        float hvv[4];
#pragma unroll
        for (int q = 0; q < 4; q++) {
            float i_ = gl[(0 * 32 + eb) * 33 + ej + q];
            float f_ = gl[(1 * 32 + eb) * 33 + ej + q];
            float g_ = gl[(2 * 32 + eb) * 33 + ej + q];
            float o_ = gl[(3 * 32 + eb) * 33 + ej + q];
            float cn = sigmf_(f_) * cv[q] + sigmf_(i_) * tanhf_(g_);
            hvv[q] = sigmf_(o_) * tanhf_(cn);
            cv[q] = cn;
        }
        // publish h to hall[t] via relaxed AGENT atomic stores (coherence point)
        {
            size_t base = ((size_t)t * NB + b0 + eb) * NPAD + jc0 + ej;
#pragma unroll
            for (int half = 0; half < 2; half++) {
                union { f16 h2[2]; unsigned u; } cvt;
                cvt.h2[0] = (f16)hvv[half * 2];
                cvt.h2[1] = (f16)hvv[half * 2 + 1];
                __hip_atomic_store((unsigned*)(hall + base + half * 2), cvt.u,
                                   __ATOMIC_RELAXED, __HIP_MEMORY_SCOPE_AGENT);
            }
        }
        const int col = jc0 + ej;
        if (col < HID_) {
            float4 o4 = make_float4(hvv[0], hvv[1], hvv[2], hvv[3]);
            *(float4*)(outl + ((size_t)(b0 + eb) * TT + t) * HID_ + col) = o4;
        }
        __syncthreads();  // drains vmcnt: h-stores visible before the signal;
                          // also: gl reads done before next step's h stage
        if (tid == 0)
            __hip_atomic_fetch_add(myflags + t, 1u, __ATOMIC_RELAXED, __HIP_MEMORY_SCOPE_AGENT);
    }
}

extern "C" void kernel_launch(void* const* d_in, const int* in_sizes, int n_in,
                              void* d_out, int out_size, void* d_ws, size_t ws_size,
                              hipStream_t stream) {
    const float* enc_in = (const float*)d_in[0];
    const float* W_ih[3] = {(const float*)d_in[1], (const float*)d_in[5], (const float*)d_in[9]};
    const float* W_hh[3] = {(const float*)d_in[2], (const float*)d_in[6], (const float*)d_in[10]};
    const float* b_ih[3] = {(const float*)d_in[3], (const float*)d_in[7], (const float*)d_in[11]};
    const float* b_hh[3] = {(const float*)d_in[4], (const float*)d_in[8], (const float*)d_in[12]};
    float* out = (float*)d_out;

    char* ws = (char*)d_ws;
    size_t off = 0;
    auto alloc = [&](size_t bytes) {
        char* p = ws + off;
        off += (bytes + 255) & ~(size_t)255;
        return p;
    };
    f16* Wih_c[3];
    f16* Whh_c[3];
    Wih_c[0] = (f16*)alloc(4ull * NPAD * DIN * sizeof(f16));
    Whh_c[0] = (f16*)alloc(4ull * NPAD * NPAD * sizeof(f16));
    Wih_c[1] = (f16*)alloc(4ull * NPAD * NPAD * sizeof(f16));
    Whh_c[1] = (f16*)alloc(4ull * NPAD * NPAD * sizeof(f16));
    Wih_c[2] = (f16*)alloc(4ull * NPAD * NPAD * sizeof(f16));
    Whh_c[2] = (f16*)alloc(4ull * NPAD * NPAD * sizeof(f16));
    float* bias_c[3];
    for (int l = 0; l < 3; l++) bias_c[l] = (float*)alloc(4ull * NPAD * sizeof(float));
    f16* xbf = (f16*)alloc((size_t)TT * NB * DIN * sizeof(f16));
    f16* hall[3];
    for (int l = 0; l < 3; l++) hall[l] = (f16*)alloc((size_t)TT * NB * NPAD * sizeof(f16));
    f16* pre = (f16*)alloc((size_t)M_ALL * 4096 * sizeof(f16));
    unsigned int* flags = (unsigned int*)alloc(3ull * 8 * TT * sizeof(unsigned int));

    hipMemsetAsync(flags, 0, 3ull * 8 * TT * sizeof(unsigned int), stream);

    conv_weight<<<512, 256, 0, stream>>>(W_ih[0], Wih_c[0], DIN, DIN);
    conv_weight<<<2048, 256, 0, stream>>>(W_hh[0], Whh_c[0], HID_, NPAD);
    conv_weight<<<2048, 256, 0, stream>>>(W_ih[1], Wih_c[1], HID_, NPAD);
    conv_weight<<<2048, 256, 0, stream>>>(W_hh[1], Whh_c[1], HID_, NPAD);
    conv_weight<<<2048, 256, 0, stream>>>(W_ih[2], Wih_c[2], HID_, NPAD);
    conv_weight<<<2048, 256, 0, stream>>>(W_hh[2], Whh_c[2], HID_, NPAD);
    conv_x<<<1024, 256, 0, stream>>>(enc_in, xbf);
    for (int l = 0; l < 3; l++)
        conv_bias<<<(4 * NPAD + 255) / 256, 256, 0, stream>>>(b_ih[l], b_hh[l], bias_c[l]);

    for (int l = 0; l < 3; l++) {
        if (l == 0)
            input_gemm<<<3136, 256, 0, stream>>>(xbf, DIN, DIN / 64, Wih_c[0], DIN,
                                                 bias_c[0], pre);
        else
            input_gemm<<<3136, 256, 0, stream>>>(hall[l - 1], NPAD, NPAD / 64, Wih_c[l], NPAD,
                                                 bias_c[l], pre);
        rec_persist<<<256, 256, 0, stream>>>(
            Whh_c[l], pre, hall[l], out + (size_t)l * NB * TT * HID_,
            flags + (size_t)l * 8 * TT);
    }
}

// Round 6
// 1157.495 us; speedup vs baseline: 4.1121x; 1.5073x over previous
//
#include <hip/hip_runtime.h>

#define HID_ 1000
#define NB 256
#define TT 49
#define DIN 192
#define NPAD 1024
#define M_ALL (TT * NB)  // 12544

typedef _Float16 f16;
typedef _Float16 f16x8 __attribute__((ext_vector_type(8)));
typedef float f32x4 __attribute__((ext_vector_type(4)));
typedef const __attribute__((address_space(1))) unsigned int* gas_u32;
typedef __attribute__((address_space(3))) unsigned int* las_u32;

__device__ __forceinline__ float sigmf_(float x) {
    return 1.0f / (1.0f + __expf(-x));
}
__device__ __forceinline__ float tanhf_(float x) {
    float ax = fabsf(x);
    float e = __expf(-2.0f * ax);
    float t = (1.0f - e) / (1.0f + e);
    return copysignf(t, x);
}

// Convert fp32 weight [4*HID_][K] -> f16 [4][NPAD][KPADv], zero-padded.
__global__ void conv_weight(const float* __restrict__ src, f16* __restrict__ dst,
                            int K, int KPADv) {
    size_t total = 4ull * NPAD * KPADv;
    for (size_t idx = (size_t)blockIdx.x * blockDim.x + threadIdx.x; idx < total;
         idx += (size_t)gridDim.x * blockDim.x) {
        int kp = (int)(idx % KPADv);
        size_t rest = idx / KPADv;
        int np = (int)(rest % NPAD);
        int g = (int)(rest / NPAD);
        f16 v = (f16)0.0f;
        if (np < HID_ && kp < K) v = (f16)src[(size_t)(g * HID_ + np) * K + kp];
        dst[idx] = v;
    }
}

// enc_in [B][T][D] fp32 -> xbf [T][B][D] f16
__global__ void conv_x(const float* __restrict__ src, f16* __restrict__ dst) {
    size_t total = (size_t)TT * NB * DIN;
    for (size_t idx = (size_t)blockIdx.x * blockDim.x + threadIdx.x; idx < total;
         idx += (size_t)gridDim.x * blockDim.x) {
        int k = (int)(idx % DIN);
        size_t rest = idx / DIN;
        int b = (int)(rest % NB);
        int t = (int)(rest / NB);
        dst[idx] = (f16)src[((size_t)b * TT + t) * DIN + k];
    }
}

// bias_c[4][NPAD] fp32 = b_ih + b_hh (zero-padded)
__global__ void conv_bias(const float* __restrict__ bih, const float* __restrict__ bhh,
                          float* __restrict__ dst) {
    int idx = blockIdx.x * blockDim.x + threadIdx.x;
    if (idx < 4 * NPAD) {
        int np = idx & (NPAD - 1);
        int g = idx >> 10;
        float v = 0.0f;
        if (np < HID_) v = bih[g * HID_ + np] + bhh[g * HID_ + np];
        dst[idx] = v;
    }
}

// pre2 = A @ W^T + bias, stored in rec's fragment order:
// pre2[(((t*8+bt)*32+jt)*4+g)*1024 + lane*16 + (mi*8+n*4+q)]  (f16)
// m97 structure: 128x128 tile, BK=64, global_load_lds, 2-barrier loop.
__global__ __launch_bounds__(256) void input_gemm(
    const f16* __restrict__ A, int lda, int kiters,
    const f16* __restrict__ W, int ldw,
    const float* __restrict__ bias,
    f16* __restrict__ pre2) {
    __shared__ f16 As[128 * 64];
    __shared__ f16 Bs[128 * 64];
    const int id = blockIdx.x;
    const int sw = (id & 7) * (gridDim.x >> 3) + (id >> 3);  // XCD swizzle (3136%8==0)
    const int m0 = (sw >> 5) << 7;
    const int n0 = (sw & 31) << 7;
    const int w = threadIdx.x >> 6;
    const int lane = threadIdx.x & 63;
    const int r = lane & 15;
    const int kb8 = (lane >> 4) << 3;  // frag k-offset (elements)
    const int wm = (w >> 1) << 6, wn = (w & 1) << 6;
    const int strow = (w << 5) + (lane >> 3);  // + q*8
    const int stcol = (lane & 7) << 3;         // elements

    f32x4 acc[4][4];
#pragma unroll
    for (int i = 0; i < 4; i++)
#pragma unroll
        for (int j = 0; j < 4; j++) acc[i][j] = (f32x4){0.f, 0.f, 0.f, 0.f};

    for (int kt = 0; kt < kiters; kt++) {
        const int k0 = kt << 6;
#pragma unroll
        for (int q = 0; q < 4; q++) {
            const int row = strow + (q << 3);
            const int cbase = ((w << 5) + (q << 3)) << 6;  // wave-uniform chunk base (elems)
            const f16* ga = A + (size_t)(m0 + row) * lda + k0 + stcol;
            const f16* gb = W + (size_t)(n0 + row) * ldw + k0 + stcol;
            __builtin_amdgcn_global_load_lds((gas_u32)ga, (las_u32)(As + cbase), 16, 0, 0);
            __builtin_amdgcn_global_load_lds((gas_u32)gb, (las_u32)(Bs + cbase), 16, 0, 0);
        }
        __syncthreads();
#pragma unroll
        for (int ks = 0; ks < 2; ks++) {
            f16x8 av[4], bv[4];
#pragma unroll
            for (int i = 0; i < 4; i++)
                av[i] = *(const f16x8*)(As + ((wm + i * 16 + r) << 6) + (ks << 5) + kb8);
#pragma unroll
            for (int j = 0; j < 4; j++)
                bv[j] = *(const f16x8*)(Bs + ((wn + j * 16 + r) << 6) + (ks << 5) + kb8);
#pragma unroll
            for (int i = 0; i < 4; i++)
#pragma unroll
                for (int j = 0; j < 4; j++)
                    acc[i][j] = __builtin_amdgcn_mfma_f32_16x16x32_f16(av[i], bv[j], acc[i][j], 0, 0, 0);
        }
        __syncthreads();
    }

    const int rbase = (lane >> 4) << 2;
#pragma unroll
    for (int j = 0; j < 4; j++) {
        const int gcol = n0 + wn + j * 16 + r;
        const float bj = bias[gcol];
        const int g = gcol >> 10, cl = gcol & 1023;
        const int jt2 = cl >> 5, c = cl & 31;
        const int n2 = c >> 4, r2 = c & 15;
#pragma unroll
        for (int i = 0; i < 4; i++) {
#pragma unroll
            for (int q = 0; q < 4; q++) {
                const int grow = m0 + wm + i * 16 + rbase + q;
                const int t_ = grow >> 8, b = grow & 255;
                const int bt2 = b >> 5, lb = b & 31;
                const int mi = lb >> 4, u2 = (lb >> 2) & 3, q2 = lb & 3;
                const int l2 = u2 * 16 + r2, flat = mi * 8 + n2 * 4 + q2;
                pre2[((((size_t)t_ * 8 + bt2) * 32 + jt2) * 4 + g) * 1024 + l2 * 16 + flat] =
                    (f16)(acc[i][j][q] + bj);
            }
        }
    }
}

// Persistent per-layer recurrent kernel. 256 wgs x 512 thr (8 waves, 2/SIMD).
// wg (bt = bid&7, jt = bid>>3): batches [bt*32,+32), cols [jt*32,+32) x 4 gates.
// Wave (g = w>>1, kh = w&1): gate g, K-half kh. wreg[2][16] = 128 VGPR.
// kh=1 writes f32 partials to LDS; kh=0 adds + finalizes. Sync scheme as round 5
// (relaxed AGENT atomics, no L2 cache maintenance).
__global__ __launch_bounds__(512, 2) void rec_persist(
    const f16* __restrict__ Whh, const f16* __restrict__ pre2,
    f16* __restrict__ hall, float* __restrict__ outl,
    unsigned int* __restrict__ flags) {
    __shared__ __align__(16) char smem[64 * 1024];  // h tile [32][2048B] swizzled; pl aliases
    float* pl = (float*)smem;                       // [4][32][36] f32 partial/final gates
    const int bid = blockIdx.x;
    const int bt = bid & 7;
    const int jt = bid >> 3;
    const int b0 = bt << 5;
    const int jc0 = jt << 5;
    const int tid = threadIdx.x;
    const int w = tid >> 6;
    const int g = w >> 1;
    const int kh = w & 1;
    const int lane = tid & 63;
    const int r = lane & 15;
    const int u = lane >> 4;
    const int kbb = u << 4;      // bytes
    const int rbase = u << 2;
    const int swz = (r & 7) << 4;

    // load this wave's K-half of the weights into registers (once per layer)
    f16x8 wreg[2][16];
#pragma unroll
    for (int n = 0; n < 2; n++) {
        const f16* wp = Whh + ((size_t)(g * NPAD + jc0 + n * 16 + r)) * NPAD + (kh << 9) + (u << 3);
#pragma unroll
        for (int ks = 0; ks < 16; ks++) wreg[n][ks] = *(const f16x8*)(wp + ks * 32);
    }

    const int eb = tid >> 4;          // epilogue batch row 0..31
    const int ej = (tid & 15) << 1;   // epilogue col (2 cols)
    float cv[2] = {0.f, 0.f};
    unsigned int* myflags = flags + bt * TT;
    const size_t preblk = ((((size_t)bt) * 32 + jt) * 4 + g) * 1024 + lane * 16;

    auto LOADP = [&](int tindex, f16x8& pa, f16x8& pb) {
        if (kh == 0) {
            const f16* pp = pre2 + (size_t)tindex * 8 * 32 * 4 * 1024 + preblk;
            pa = *(const f16x8*)pp;
            pb = *(const f16x8*)(pp + 8);
        }
    };

    auto STEP = [&](int t, f16x8& pc0, f16x8& pc1, f16x8& pn0, f16x8& pn1) {
        if (t > 0) {
            if (tid == 0) {
                while (__hip_atomic_load(myflags + (t - 1), __ATOMIC_RELAXED,
                                         __HIP_MEMORY_SCOPE_AGENT) < 32u) {}
            }
            __syncthreads();
            asm volatile("" ::: "memory");
            // stage h = hall[t-1] rows b0..b0+31 -> LDS (XOR-swizzled rows)
            const f16* hread = hall + (size_t)(t - 1) * NB * NPAD;
#pragma unroll
            for (int i = 0; i < 8; i++) {
                int c = tid + (i << 9);
                int row = c >> 7;
                int cb = (c & 127) << 4;
                f16x8 v = *(const f16x8*)(hread + (size_t)(b0 + row) * NPAD + (cb >> 1));
                *(f16x8*)(smem + row * 2048 + (cb ^ ((row & 7) << 4))) = v;
            }
            __syncthreads();
        }

        // prefetch next step's pre2 block (hidden under MFMA)
        LOADP(t + 1 < TT ? t + 1 : t, pn0, pn1);

        // acc init: kh=0 from pre2 fragment regs, kh=1 zero
        f32x4 acc[2][2];
#pragma unroll
        for (int mi = 0; mi < 2; mi++)
#pragma unroll
            for (int n = 0; n < 2; n++)
#pragma unroll
                for (int q = 0; q < 4; q++) {
                    if (kh == 0)
                        acc[mi][n][q] = (float)(mi == 0 ? pc0[n * 4 + q] : pc1[n * 4 + q]);
                    else
                        acc[mi][n][q] = 0.f;
                }

        if (t > 0) {
#pragma unroll
            for (int ks = 0; ks < 16; ks++) {
                const int ksg = (kh << 4) + ks;
                f16x8 a0 = *(const f16x8*)(smem + r * 2048 + ((ksg * 64 + kbb) ^ swz));
                f16x8 a1 = *(const f16x8*)(smem + (16 + r) * 2048 + ((ksg * 64 + kbb) ^ swz));
                acc[0][0] = __builtin_amdgcn_mfma_f32_16x16x32_f16(a0, wreg[0][ks], acc[0][0], 0, 0, 0);
                acc[0][1] = __builtin_amdgcn_mfma_f32_16x16x32_f16(a0, wreg[1][ks], acc[0][1], 0, 0, 0);
                acc[1][0] = __builtin_amdgcn_mfma_f32_16x16x32_f16(a1, wreg[0][ks], acc[1][0], 0, 0, 0);
                acc[1][1] = __builtin_amdgcn_mfma_f32_16x16x32_f16(a1, wreg[1][ks], acc[1][1], 0, 0, 0);
            }
        }
        __syncthreads();  // all h-LDS reads done before pl aliases smem

        // K-half reduction through LDS: kh=1 writes partials, kh=0 adds + finalizes
        if (kh == 1) {
#pragma unroll
            for (int mi = 0; mi < 2; mi++)
#pragma unroll
                for (int n = 0; n < 2; n++)
#pragma unroll
                    for (int q = 0; q < 4; q++)
                        pl[(g * 32 + mi * 16 + rbase + q) * 36 + n * 16 + r] = acc[mi][n][q];
        }
        __syncthreads();
        if (kh == 0) {
#pragma unroll
            for (int mi = 0; mi < 2; mi++)
#pragma unroll
                for (int n = 0; n < 2; n++)
#pragma unroll
                    for (int q = 0; q < 4; q++) {
                        const int idx = (g * 32 + mi * 16 + rbase + q) * 36 + n * 16 + r;
                        pl[idx] = pl[idx] + acc[mi][n][q];
                    }
        }
        __syncthreads();

        // cell update: thread -> (eb, ej..ej+1)
        float hvv[2];
#pragma unroll
        for (int q = 0; q < 2; q++) {
            float i_ = pl[(0 * 32 + eb) * 36 + ej + q];
            float f_ = pl[(1 * 32 + eb) * 36 + ej + q];
            float g_ = pl[(2 * 32 + eb) * 36 + ej + q];
            float o_ = pl[(3 * 32 + eb) * 36 + ej + q];
            float cn = sigmf_(f_) * cv[q] + sigmf_(i_) * tanhf_(g_);
            hvv[q] = sigmf_(o_) * tanhf_(cn);
            cv[q] = cn;
        }
        // publish h to hall[t] via relaxed AGENT atomic store (coherence point)
        {
            union { f16 h2[2]; unsigned uu; } cvt;
            cvt.h2[0] = (f16)hvv[0];
            cvt.h2[1] = (f16)hvv[1];
            __hip_atomic_store(
                (unsigned*)(hall + ((size_t)t * NB + b0 + eb) * NPAD + jc0 + ej), cvt.uu,
                __ATOMIC_RELAXED, __HIP_MEMORY_SCOPE_AGENT);
        }
        const int col = jc0 + ej;
        if (col < HID_) {
            *(float2*)(outl + ((size_t)(b0 + eb) * TT + t) * HID_ + col) =
                make_float2(hvv[0], hvv[1]);
        }
        __syncthreads();  // vmcnt drain: h-stores visible before signal; pl reads done
        if (tid == 0)
            __hip_atomic_fetch_add(myflags + t, 1u, __ATOMIC_RELAXED, __HIP_MEMORY_SCOPE_AGENT);
    };

    f16x8 pA0 = {}, pA1 = {}, pB0 = {}, pB1 = {};
    LOADP(0, pA0, pA1);
    for (int t = 0; t < TT; t += 2) {
        STEP(t, pA0, pA1, pB0, pB1);
        if (t + 1 < TT) STEP(t + 1, pB0, pB1, pA0, pA1);
    }
}

extern "C" void kernel_launch(void* const* d_in, const int* in_sizes, int n_in,
                              void* d_out, int out_size, void* d_ws, size_t ws_size,
                              hipStream_t stream) {
    const float* enc_in = (const float*)d_in[0];
    const float* W_ih[3] = {(const float*)d_in[1], (const float*)d_in[5], (const float*)d_in[9]};
    const float* W_hh[3] = {(const float*)d_in[2], (const float*)d_in[6], (const float*)d_in[10]};
    const float* b_ih[3] = {(const float*)d_in[3], (const float*)d_in[7], (const float*)d_in[11]};
    const float* b_hh[3] = {(const float*)d_in[4], (const float*)d_in[8], (const float*)d_in[12]};
    float* out = (float*)d_out;

    char* ws = (char*)d_ws;
    size_t off = 0;
    auto alloc = [&](size_t bytes) {
        char* p = ws + off;
        off += (bytes + 255) & ~(size_t)255;
        return p;
    };
    f16* Wih_c[3];
    f16* Whh_c[3];
    Wih_c[0] = (f16*)alloc(4ull * NPAD * DIN * sizeof(f16));
    Whh_c[0] = (f16*)alloc(4ull * NPAD * NPAD * sizeof(f16));
    Wih_c[1] = (f16*)alloc(4ull * NPAD * NPAD * sizeof(f16));
    Whh_c[1] = (f16*)alloc(4ull * NPAD * NPAD * sizeof(f16));
    Wih_c[2] = (f16*)alloc(4ull * NPAD * NPAD * sizeof(f16));
    Whh_c[2] = (f16*)alloc(4ull * NPAD * NPAD * sizeof(f16));
    float* bias_c[3];
    for (int l = 0; l < 3; l++) bias_c[l] = (float*)alloc(4ull * NPAD * sizeof(float));
    f16* xbf = (f16*)alloc((size_t)TT * NB * DIN * sizeof(f16));
    f16* hall[3];
    for (int l = 0; l < 3; l++) hall[l] = (f16*)alloc((size_t)TT * NB * NPAD * sizeof(f16));
    f16* pre2 = (f16*)alloc((size_t)M_ALL * 4096 * sizeof(f16));
    unsigned int* flags = (unsigned int*)alloc(3ull * 8 * TT * sizeof(unsigned int));

    hipMemsetAsync(flags, 0, 3ull * 8 * TT * sizeof(unsigned int), stream);

    conv_weight<<<512, 256, 0, stream>>>(W_ih[0], Wih_c[0], DIN, DIN);
    conv_weight<<<2048, 256, 0, stream>>>(W_hh[0], Whh_c[0], HID_, NPAD);
    conv_weight<<<2048, 256, 0, stream>>>(W_ih[1], Wih_c[1], HID_, NPAD);
    conv_weight<<<2048, 256, 0, stream>>>(W_hh[1], Whh_c[1], HID_, NPAD);
    conv_weight<<<2048, 256, 0, stream>>>(W_ih[2], Wih_c[2], HID_, NPAD);
    conv_weight<<<2048, 256, 0, stream>>>(W_hh[2], Whh_c[2], HID_, NPAD);
    conv_x<<<1024, 256, 0, stream>>>(enc_in, xbf);
    for (int l = 0; l < 3; l++)
        conv_bias<<<(4 * NPAD + 255) / 256, 256, 0, stream>>>(b_ih[l], b_hh[l], bias_c[l]);

    for (int l = 0; l < 3; l++) {
        if (l == 0)
            input_gemm<<<3136, 256, 0, stream>>>(xbf, DIN, DIN / 64, Wih_c[0], DIN,
                                                 bias_c[0], pre2);
        else
            input_gemm<<<3136, 256, 0, stream>>>(hall[l - 1], NPAD, NPAD / 64, Wih_c[l], NPAD,
                                                 bias_c[l], pre2);
        rec_persist<<<256, 512, 0, stream>>>(
            Whh_c[l], pre2, hall[l], out + (size_t)l * NB * TT * HID_,
            flags + (size_t)l * 8 * TT);
    }
}